// Round 1
// baseline (494.749 us; speedup 1.0000x reference)
//
#include <hip/hip_runtime.h>
#include <math.h>

// B=16 P=16 I=16 L=64 D=128 F=128 C=1024
#define Bb 16
#define Pp 16
#define Ii 16
#define Ll 64
#define Dd 128
#define Ff 128
#define Cc 1024

static __device__ __forceinline__ float dot4(float4 a, float4 b) {
    return a.x*b.x + a.y*b.y + a.z*b.z + a.w*b.w;
}

// ---------------- Kernel 1: masked mean over L + conv projection ----------
// grid = B*P*I = 4096 blocks, 256 threads
__global__ __launch_bounds__(256) void k_mean_conv(
    const float* __restrict__ path_emb, const int* __restrict__ path_len,
    const float* __restrict__ conv_w, const float* __restrict__ conv_b,
    float* __restrict__ inst)
{
    int bpi = blockIdx.x;
    int t = threadIdx.x;
    int len = path_len[bpi];
    const float4* base = (const float4*)(path_emb + (size_t)bpi * Ll * Dd);
    int quad = t & 31;      // which float4 of the 128-float row
    int lr = t >> 5;        // 0..7 row group
    float4 acc = make_float4(0.f, 0.f, 0.f, 0.f);
    for (int l = lr; l < len; l += 8) {
        float4 v = base[l * 32 + quad];
        acc.x += v.x; acc.y += v.y; acc.z += v.z; acc.w += v.w;
    }
    __shared__ float4 red[256];
    __shared__ float4 mean4[32];
    red[t] = acc;
    __syncthreads();
    if (t < 32) {
        float4 s = red[t];
#pragma unroll
        for (int g = 1; g < 8; ++g) {
            float4 v = red[t + 32 * g];
            s.x += v.x; s.y += v.y; s.z += v.z; s.w += v.w;
        }
        float inv = 1.0f / (float)len;
        s.x *= inv; s.y *= inv; s.z *= inv; s.w *= inv;
        mean4[t] = s;
    }
    __syncthreads();
    if (t < 128) {
        const float4* w = (const float4*)(conv_w + (size_t)t * Dd);
        float a = conv_b[t];
#pragma unroll 8
        for (int dq = 0; dq < 32; ++dq) a += dot4(mean4[dq], w[dq]);
        inst[(size_t)bpi * Ff + t] = a;
    }
}

// ---------------- Kernel 2: pia MHA over I, fused mean -> meta -----------
// grid = B*P = 256 blocks, 256 threads
__global__ __launch_bounds__(256) void k_pia(
    const float* __restrict__ inst,
    const float* __restrict__ in_w, const float* __restrict__ in_b,
    const float* __restrict__ out_w, const float* __restrict__ out_b,
    float* __restrict__ meta)
{
    __shared__ float4 xs[16 * 33];
    __shared__ float4 qs[16 * 33];
    __shared__ float4 ks[16 * 33];
    __shared__ float4 vs[16 * 33];
    __shared__ float Ss[16 * 17];
    __shared__ float wj[16];
    __shared__ float4 z4[32];
    int t = threadIdx.x;
    int bp = blockIdx.x;

    const float4* xin = (const float4*)(inst + (size_t)bp * 16 * Ff);
    for (int idx = t; idx < 512; idx += 256)
        xs[(idx >> 5) * 33 + (idx & 31)] = xin[idx];
    __syncthreads();

    // qkv: thread computes 24 outputs j = jb+16r for row i
    int i = t & 15, jb = t >> 4;
    float acc[24];
#pragma unroll
    for (int r = 0; r < 24; ++r) acc[r] = in_b[jb + 16 * r];
    const float4* w4 = (const float4*)in_w;
    for (int dq = 0; dq < 32; ++dq) {
        float4 xa = xs[i * 33 + dq];
#pragma unroll
        for (int r = 0; r < 24; ++r)
            acc[r] += dot4(xa, w4[(jb + 16 * r) * 32 + dq]);
    }
    float* qsf = (float*)qs; float* ksf = (float*)ks; float* vsf = (float*)vs;
#pragma unroll
    for (int r = 0; r < 8; ++r) qsf[i * 132 + jb + 16 * r] = acc[r];
#pragma unroll
    for (int r = 0; r < 8; ++r) ksf[i * 132 + jb + 16 * r] = acc[r + 8];
#pragma unroll
    for (int r = 0; r < 8; ++r) vsf[i * 132 + jb + 16 * r] = acc[r + 16];
    __syncthreads();

    // S = q k^T / sqrt(128)
    {
        int si = t >> 4, sj = t & 15;
        float s = 0.f;
#pragma unroll 8
        for (int dq = 0; dq < 32; ++dq)
            s += dot4(qs[si * 33 + dq], ks[sj * 33 + dq]);
        Ss[si * 17 + sj] = s * 0.08838834764831843f;
    }
    __syncthreads();
    // softmax each row
    if (t < 16) {
        float mx = -1e30f;
        for (int j = 0; j < 16; ++j) mx = fmaxf(mx, Ss[t * 17 + j]);
        float e[16]; float sum = 0.f;
        for (int j = 0; j < 16; ++j) { e[j] = expf(Ss[t * 17 + j] - mx); sum += e[j]; }
        float inv = 1.0f / sum;
        for (int j = 0; j < 16; ++j) Ss[t * 17 + j] = e[j] * inv;
    }
    __syncthreads();
    // column mean of attn (mean over i commutes through attn@v)
    if (t < 16) {
        float s = 0.f;
        for (int i2 = 0; i2 < 16; ++i2) s += Ss[i2 * 17 + t];
        wj[t] = s * (1.0f / 16.0f);
    }
    __syncthreads();
    // z[d] = sum_j wj[j] * v[j][d]
    if (t < 128) {
        float s = 0.f;
#pragma unroll
        for (int j = 0; j < 16; ++j) s += wj[j] * vsf[j * 132 + t];
        ((float*)z4)[t] = s;
    }
    __syncthreads();
    // meta[f] = z . out_w[f] + out_b[f]
    if (t < 128) {
        const float4* w = (const float4*)(out_w + (size_t)t * Ff);
        float a = out_b[t];
#pragma unroll 8
        for (int dq = 0; dq < 32; ++dq) a += dot4(z4[dq], w[dq]);
        meta[(size_t)bp * Ff + t] = a;
    }
}

// ---------------- Kernel 3: mpa MHA over P + qia + base scalar -----------
// grid = B = 16 blocks, 256 threads
__global__ __launch_bounds__(256) void k_mpa_qia(
    const float* __restrict__ meta, const float* __restrict__ query,
    const float* __restrict__ in_w, const float* __restrict__ in_b,
    const float* __restrict__ out_w, const float* __restrict__ out_b,
    const float* __restrict__ qia_in_w, const float* __restrict__ qia_in_b,
    const float* __restrict__ qia_out_w, const float* __restrict__ qia_out_b,
    const float* __restrict__ score_w, const float* __restrict__ score_b,
    float* __restrict__ baseout)
{
    __shared__ float4 xs[16 * 33];
    __shared__ float4 qs[16 * 33];
    __shared__ float4 ks[16 * 33];
    __shared__ float4 vs[16 * 33];
    __shared__ float Ss[16 * 17];
    __shared__ float wj[16];
    __shared__ float4 z4[32];
    __shared__ float v1s[128];
    __shared__ float4 mm4[32];
    __shared__ float4 tq4[32];
    __shared__ float v2s[128];
    __shared__ float red[128];
    int t = threadIdx.x;
    int b = blockIdx.x;
    float* xsf = (float*)xs;

    const float4* xin = (const float4*)(meta + (size_t)b * 16 * Ff);
    for (int idx = t; idx < 512; idx += 256)
        xs[(idx >> 5) * 33 + (idx & 31)] = xin[idx];
    __syncthreads();

    int i = t & 15, jb = t >> 4;
    float acc[24];
#pragma unroll
    for (int r = 0; r < 24; ++r) acc[r] = in_b[jb + 16 * r];
    const float4* w4 = (const float4*)in_w;
    for (int dq = 0; dq < 32; ++dq) {
        float4 xa = xs[i * 33 + dq];
#pragma unroll
        for (int r = 0; r < 24; ++r)
            acc[r] += dot4(xa, w4[(jb + 16 * r) * 32 + dq]);
    }
    float* qsf = (float*)qs; float* ksf = (float*)ks; float* vsf = (float*)vs;
#pragma unroll
    for (int r = 0; r < 8; ++r) qsf[i * 132 + jb + 16 * r] = acc[r];
#pragma unroll
    for (int r = 0; r < 8; ++r) ksf[i * 132 + jb + 16 * r] = acc[r + 8];
#pragma unroll
    for (int r = 0; r < 8; ++r) vsf[i * 132 + jb + 16 * r] = acc[r + 16];
    __syncthreads();

    {
        int si = t >> 4, sj = t & 15;
        float s = 0.f;
#pragma unroll 8
        for (int dq = 0; dq < 32; ++dq)
            s += dot4(qs[si * 33 + dq], ks[sj * 33 + dq]);
        Ss[si * 17 + sj] = s * 0.08838834764831843f;
    }
    __syncthreads();
    if (t < 16) {
        float mx = -1e30f;
        for (int j = 0; j < 16; ++j) mx = fmaxf(mx, Ss[t * 17 + j]);
        float e[16]; float sum = 0.f;
        for (int j = 0; j < 16; ++j) { e[j] = expf(Ss[t * 17 + j] - mx); sum += e[j]; }
        float inv = 1.0f / sum;
        for (int j = 0; j < 16; ++j) Ss[t * 17 + j] = e[j] * inv;
    }
    __syncthreads();
    if (t < 16) {
        float s = 0.f;
        for (int i2 = 0; i2 < 16; ++i2) s += Ss[i2 * 17 + t];
        wj[t] = s * (1.0f / 16.0f);
    }
    __syncthreads();
    if (t < 128) {
        float s = 0.f;
#pragma unroll
        for (int j = 0; j < 16; ++j) s += wj[j] * vsf[j * 132 + t];
        ((float*)z4)[t] = s;
    }
    __syncthreads();
    // v1[f]
    if (t < 128) {
        const float4* w = (const float4*)(out_w + (size_t)t * Ff);
        float a = out_b[t];
#pragma unroll 8
        for (int dq = 0; dq < 32; ++dq) a += dot4(z4[dq], w[dq]);
        v1s[t] = a;
    }
    __syncthreads();
    // mm[d] = mean_p x[p][d]
    if (t < 128) {
        float s = 0.f;
#pragma unroll
        for (int p = 0; p < 16; ++p) s += xsf[p * 132 + t];
        ((float*)mm4)[t] = s * (1.0f / 16.0f);
    }
    __syncthreads();
    // tq[f] = mm . qia_in_w[256+f] + qia_in_b[256+f]
    if (t < 128) {
        const float4* w = (const float4*)(qia_in_w + (size_t)(256 + t) * Ff);
        float a = qia_in_b[256 + t];
#pragma unroll 8
        for (int dq = 0; dq < 32; ++dq) a += dot4(mm4[dq], w[dq]);
        ((float*)tq4)[t] = a;
    }
    __syncthreads();
    // v2[f] = tq . qia_out_w[f] + qia_out_b[f]
    if (t < 128) {
        const float4* w = (const float4*)(qia_out_w + (size_t)t * Ff);
        float a = qia_out_b[t];
#pragma unroll 8
        for (int dq = 0; dq < 32; ++dq) a += dot4(tq4[dq], w[dq]);
        v2s[t] = a;
    }
    __syncthreads();
    // base[b] = q.sw0 + v1.sw1 + v2.sw2 + score_b
    if (t < 128) {
        red[t] = query[(size_t)b * Dd + t] * score_w[t]
               + v1s[t] * score_w[128 + t]
               + v2s[t] * score_w[256 + t];
    }
    __syncthreads();
    for (int s = 64; s > 0; s >>= 1) {
        if (t < s) red[t] += red[t + s];
        __syncthreads();
    }
    if (t == 0) baseout[b] = red[0] + score_b[0];
}

// ---------------- Kernel 4a: cand scores -> exp, per-b sum ---------------
// grid = B*P*8 = 2048 blocks, 256 threads; each block does 128 candidates
__global__ __launch_bounds__(256) void k_score(
    const float* __restrict__ cand_emb, const int* __restrict__ cand_len,
    const float* __restrict__ score_w, const float* __restrict__ basev,
    float* __restrict__ eout, float* __restrict__ sumexp)
{
    int blk = blockIdx.x;
    int chunk = blk & 7;
    int bp = blk >> 3;
    int b = bp >> 4;
    int t = threadIdx.x;
    int quad = t & 31, cl = t >> 5;   // 8 candidates concurrently
    float4 swq = ((const float4*)(score_w + 384))[quad];
    float bb = basev[b];
    int clen = cand_len[bp];
    const float4* cbase = (const float4*)(cand_emb + ((size_t)bp * Cc + chunk * 128) * Dd);
    float lsum = 0.f;
#pragma unroll 4
    for (int it = 0; it < 16; ++it) {
        int c = cl + it * 8;          // local candidate 0..127
        float4 v = cbase[(size_t)c * 32 + quad];
        float part = dot4(v, swq);
        part += __shfl_xor(part, 16);
        part += __shfl_xor(part, 8);
        part += __shfl_xor(part, 4);
        part += __shfl_xor(part, 2);
        part += __shfl_xor(part, 1);
        int gc = chunk * 128 + c;
        float e = (gc < clen) ? expf(part + bb) : 0.0f;
        if (quad == 0) {
            eout[(size_t)bp * Cc + gc] = e;
            lsum += e;
        }
    }
    __shared__ float red[256];
    red[t] = lsum;
    __syncthreads();
    for (int s = 128; s > 0; s >>= 1) {
        if (t < s) red[t] += red[t + s];
        __syncthreads();
    }
    if (t == 0) atomicAdd(&sumexp[b], red[0]);
}

// ---------------- Kernel 4b: normalize ------------------------------------
// grid = 256 blocks * 256 threads, one float4 each (65536 float4 total)
__global__ __launch_bounds__(256) void k_norm(
    float* __restrict__ out, const float* __restrict__ sumexp)
{
    int idx = blockIdx.x * 256 + threadIdx.x;
    int b = idx >> 12;  // 4096 float4 per batch
    float inv = 1.0f / sumexp[b];
    float4* o4 = (float4*)out;
    float4 v = o4[idx];
    v.x *= inv; v.y *= inv; v.z *= inv; v.w *= inv;
    o4[idx] = v;
}

extern "C" void kernel_launch(void* const* d_in, const int* in_sizes, int n_in,
                              void* d_out, int out_size, void* d_ws, size_t ws_size,
                              hipStream_t stream)
{
    const float* query    = (const float*)d_in[0];
    const float* path_emb = (const float*)d_in[1];
    const int*   path_len = (const int*)  d_in[2];
    const float* cand_emb = (const float*)d_in[3];
    const int*   cand_len = (const int*)  d_in[4];
    const float* conv_w   = (const float*)d_in[5];
    const float* conv_b   = (const float*)d_in[6];
    const float* pia_in_w = (const float*)d_in[7];
    const float* pia_in_b = (const float*)d_in[8];
    const float* pia_out_w= (const float*)d_in[9];
    const float* pia_out_b= (const float*)d_in[10];
    const float* mpa_in_w = (const float*)d_in[11];
    const float* mpa_in_b = (const float*)d_in[12];
    const float* mpa_out_w= (const float*)d_in[13];
    const float* mpa_out_b= (const float*)d_in[14];
    const float* qia_in_w = (const float*)d_in[15];
    const float* qia_in_b = (const float*)d_in[16];
    const float* qia_out_w= (const float*)d_in[17];
    const float* qia_out_b= (const float*)d_in[18];
    const float* score_w  = (const float*)d_in[19];
    const float* score_b  = (const float*)d_in[20];
    float* out = (float*)d_out;

    float* ws     = (float*)d_ws;
    float* inst   = ws;                       // B*P*I*F = 524288
    float* meta   = ws + 524288;              // B*P*F   = 32768
    float* basev  = ws + 524288 + 32768;      // B       = 16
    float* sumexp = basev + 16;               // B       = 16

    hipMemsetAsync(sumexp, 0, Bb * sizeof(float), stream);

    k_mean_conv<<<Bb * Pp * Ii, 256, 0, stream>>>(path_emb, path_len, conv_w, conv_b, inst);
    k_pia<<<Bb * Pp, 256, 0, stream>>>(inst, pia_in_w, pia_in_b, pia_out_w, pia_out_b, meta);
    k_mpa_qia<<<Bb, 256, 0, stream>>>(meta, query,
                                      mpa_in_w, mpa_in_b, mpa_out_w, mpa_out_b,
                                      qia_in_w, qia_in_b, qia_out_w, qia_out_b,
                                      score_w, score_b, basev);
    k_score<<<Bb * Pp * 8, 256, 0, stream>>>(cand_emb, cand_len, score_w, basev, out, sumexp);
    k_norm<<<256, 256, 0, stream>>>(out, sumexp);
}

// Round 2
// 440.656 us; speedup vs baseline: 1.1228x; 1.1228x over previous
//
#include <hip/hip_runtime.h>
#include <math.h>

// B=16 P=16 I=16 L=64 D=128 F=128 C=1024
#define Bb 16
#define Pp 16
#define Ii 16
#define Ll 64
#define Dd 128
#define Ff 128
#define Cc 1024

static __device__ __forceinline__ float dot4(float4 a, float4 b) {
    return a.x*b.x + a.y*b.y + a.z*b.z + a.w*b.w;
}

// ---------------- Kernel 1: masked mean over L + conv projection ----------
// grid = B*P*I = 4096 blocks, 256 threads
__global__ __launch_bounds__(256) void k_mean_conv(
    const float* __restrict__ path_emb, const int* __restrict__ path_len,
    const float* __restrict__ conv_w, const float* __restrict__ conv_b,
    float* __restrict__ inst)
{
    int bpi = blockIdx.x;
    int t = threadIdx.x;
    int len = path_len[bpi];
    const float4* base = (const float4*)(path_emb + (size_t)bpi * Ll * Dd);
    int quad = t & 31;      // which float4 of the 128-float row
    int lr = t >> 5;        // 0..7 row group
    float4 acc = make_float4(0.f, 0.f, 0.f, 0.f);
    for (int l = lr; l < len; l += 8) {
        float4 v = base[l * 32 + quad];
        acc.x += v.x; acc.y += v.y; acc.z += v.z; acc.w += v.w;
    }
    __shared__ float4 red[256];
    __shared__ float4 mean4[32];
    red[t] = acc;
    __syncthreads();
    if (t < 32) {
        float4 s = red[t];
#pragma unroll
        for (int g = 1; g < 8; ++g) {
            float4 v = red[t + 32 * g];
            s.x += v.x; s.y += v.y; s.z += v.z; s.w += v.w;
        }
        float inv = 1.0f / (float)len;
        s.x *= inv; s.y *= inv; s.z *= inv; s.w *= inv;
        mean4[t] = s;
    }
    __syncthreads();
    if (t < 128) {
        const float4* w = (const float4*)(conv_w + (size_t)t * Dd);
        float a = conv_b[t];
#pragma unroll 8
        for (int dq = 0; dq < 32; ++dq) a += dot4(mean4[dq], w[dq]);
        inst[(size_t)bpi * Ff + t] = a;
    }
}

// ---------------- Kernel 2: pia MHA over I, fused mean -> meta -----------
// grid = B*P = 256 blocks, 256 threads
__global__ __launch_bounds__(256) void k_pia(
    const float* __restrict__ inst,
    const float* __restrict__ in_w, const float* __restrict__ in_b,
    const float* __restrict__ out_w, const float* __restrict__ out_b,
    float* __restrict__ meta)
{
    __shared__ float4 xs[16 * 33];
    __shared__ float4 qs[16 * 33];
    __shared__ float4 ks[16 * 33];
    __shared__ float4 vs[16 * 33];
    __shared__ float Ss[16 * 17];
    __shared__ float wj[16];
    __shared__ float4 z4[32];
    int t = threadIdx.x;
    int bp = blockIdx.x;

    const float4* xin = (const float4*)(inst + (size_t)bp * 16 * Ff);
    for (int idx = t; idx < 512; idx += 256)
        xs[(idx >> 5) * 33 + (idx & 31)] = xin[idx];
    __syncthreads();

    // qkv: thread computes 24 outputs j = jb+16r for row i
    int i = t & 15, jb = t >> 4;
    float acc[24];
#pragma unroll
    for (int r = 0; r < 24; ++r) acc[r] = in_b[jb + 16 * r];
    const float4* w4 = (const float4*)in_w;
    for (int dq = 0; dq < 32; ++dq) {
        float4 xa = xs[i * 33 + dq];
#pragma unroll
        for (int r = 0; r < 24; ++r)
            acc[r] += dot4(xa, w4[(jb + 16 * r) * 32 + dq]);
    }
    float* qsf = (float*)qs; float* ksf = (float*)ks; float* vsf = (float*)vs;
#pragma unroll
    for (int r = 0; r < 8; ++r) qsf[i * 132 + jb + 16 * r] = acc[r];
#pragma unroll
    for (int r = 0; r < 8; ++r) ksf[i * 132 + jb + 16 * r] = acc[r + 8];
#pragma unroll
    for (int r = 0; r < 8; ++r) vsf[i * 132 + jb + 16 * r] = acc[r + 16];
    __syncthreads();

    // S = q k^T / sqrt(128)
    {
        int si = t >> 4, sj = t & 15;
        float s = 0.f;
#pragma unroll 8
        for (int dq = 0; dq < 32; ++dq)
            s += dot4(qs[si * 33 + dq], ks[sj * 33 + dq]);
        Ss[si * 17 + sj] = s * 0.08838834764831843f;
    }
    __syncthreads();
    // softmax each row
    if (t < 16) {
        float mx = -1e30f;
        for (int j = 0; j < 16; ++j) mx = fmaxf(mx, Ss[t * 17 + j]);
        float e[16]; float sum = 0.f;
        for (int j = 0; j < 16; ++j) { e[j] = expf(Ss[t * 17 + j] - mx); sum += e[j]; }
        float inv = 1.0f / sum;
        for (int j = 0; j < 16; ++j) Ss[t * 17 + j] = e[j] * inv;
    }
    __syncthreads();
    // column mean of attn (mean over i commutes through attn@v)
    if (t < 16) {
        float s = 0.f;
        for (int i2 = 0; i2 < 16; ++i2) s += Ss[i2 * 17 + t];
        wj[t] = s * (1.0f / 16.0f);
    }
    __syncthreads();
    // z[d] = sum_j wj[j] * v[j][d]
    if (t < 128) {
        float s = 0.f;
#pragma unroll
        for (int j = 0; j < 16; ++j) s += wj[j] * vsf[j * 132 + t];
        ((float*)z4)[t] = s;
    }
    __syncthreads();
    // meta[f] = z . out_w[f] + out_b[f]
    if (t < 128) {
        const float4* w = (const float4*)(out_w + (size_t)t * Ff);
        float a = out_b[t];
#pragma unroll 8
        for (int dq = 0; dq < 32; ++dq) a += dot4(z4[dq], w[dq]);
        meta[(size_t)bp * Ff + t] = a;
    }
}

// ---------------- Kernel 3a: mpa QKV projection (wide-parallel GEMM) -----
// grid = B * 24 = 384 blocks, 256 threads; block = (b, 16-row chunk of in_w)
// qkv layout: [b][i(16)][row(384)]
__global__ __launch_bounds__(256) void k_mpa_qkv(
    const float* __restrict__ meta,
    const float* __restrict__ in_w, const float* __restrict__ in_b,
    float* __restrict__ qkv)
{
    int blk = blockIdx.x;
    int b = blk / 24, jc = blk % 24;
    int t = threadIdx.x;
    int i = t >> 4;        // 0..15 input row
    int jl = t & 15;       // lane-fast over weight rows -> 16 distinct rows/instr
    int jg = jc * 16 + jl; // global qkv row 0..383
    const float4* x4 = (const float4*)(meta) + (size_t)b * 512 + i * 32;
    const float4* w4 = (const float4*)(in_w) + (size_t)jg * 32;
    float a = in_b[jg];
#pragma unroll 8
    for (int dq = 0; dq < 32; ++dq) a += dot4(x4[dq], w4[dq]);
    qkv[(size_t)b * 6144 + i * 384 + jg] = a;
}

// ---------------- Kernel 3b: mpa attention + qia + base, per b ----------
// grid = B = 16 blocks, 256 threads. One weight ROW PER LANE everywhere:
// 64 distinct rows x 16B = 1KB per load instr, 32 independent loads/thread.
__global__ __launch_bounds__(256) void k_mpa_post(
    const float* __restrict__ qkv, const float* __restrict__ meta,
    const float* __restrict__ query,
    const float* __restrict__ out_w, const float* __restrict__ out_b,
    const float* __restrict__ qia_in_w, const float* __restrict__ qia_in_b,
    const float* __restrict__ qia_out_w, const float* __restrict__ qia_out_b,
    const float* __restrict__ score_w, const float* __restrict__ score_b,
    float* __restrict__ basev)
{
    __shared__ float4 qs[16 * 33];
    __shared__ float4 ks[16 * 33];
    __shared__ float4 vs[16 * 33];
    __shared__ float Ss[16 * 17];
    __shared__ float wj[16];
    __shared__ float4 z4[32];
    __shared__ float4 mm4[32];
    __shared__ float v1s[128];
    __shared__ float4 tq4[32];
    __shared__ float v2s[128];
    __shared__ float red[128];
    int t = threadIdx.x, b = blockIdx.x;
    float* vsf = (float*)vs;

    // stage qkv[b] (16 x 384) into q/k/v LDS tiles (padded rows of 33 float4)
    const float4* src = (const float4*)(qkv + (size_t)b * 6144);
    for (int idx = t; idx < 1536; idx += 256) {
        int i = idx / 96, q = idx - i * 96;
        float4 v = src[idx];
        if (q < 32)       qs[i * 33 + q]        = v;
        else if (q < 64)  ks[i * 33 + (q - 32)] = v;
        else              vs[i * 33 + (q - 64)] = v;
    }
    // mm[d] = mean_p meta[b][p][d] (global, coalesced per p)
    float mmacc = 0.f;
    if (t < 128) {
#pragma unroll
        for (int p = 0; p < 16; ++p) mmacc += meta[(size_t)b * 2048 + p * 128 + t];
        mmacc *= (1.0f / 16.0f);
    }
    __syncthreads();

    // S = q k^T / sqrt(128)
    {
        int si = t >> 4, sj = t & 15;
        float s = 0.f;
#pragma unroll 8
        for (int dq = 0; dq < 32; ++dq)
            s += dot4(qs[si * 33 + dq], ks[sj * 33 + dq]);
        Ss[si * 17 + sj] = s * 0.08838834764831843f;
    }
    if (t < 128) ((float*)mm4)[t] = mmacc;
    __syncthreads();
    // softmax rows
    if (t < 16) {
        float mx = -1e30f;
        for (int j = 0; j < 16; ++j) mx = fmaxf(mx, Ss[t * 17 + j]);
        float e[16]; float sum = 0.f;
        for (int j = 0; j < 16; ++j) { e[j] = expf(Ss[t * 17 + j] - mx); sum += e[j]; }
        float inv = 1.0f / sum;
        for (int j = 0; j < 16; ++j) Ss[t * 17 + j] = e[j] * inv;
    }
    __syncthreads();
    // column mean of attn
    if (t < 16) {
        float s = 0.f;
        for (int i2 = 0; i2 < 16; ++i2) s += Ss[i2 * 17 + t];
        wj[t] = s * (1.0f / 16.0f);
    }
    __syncthreads();
    // z[d] = sum_j wj[j] * v[j][d]
    if (t < 128) {
        float s = 0.f;
#pragma unroll
        for (int j = 0; j < 16; ++j) s += wj[j] * vsf[j * 132 + t];
        ((float*)z4)[t] = s;
    }
    __syncthreads();

    // phase A: t<128 -> v1[f] = z . out_w[f] + out_b[f]
    //          t>=128 -> tq[f] = mm . qia_in_w[256+f] + qia_in_b[256+f]
    if (t < 128) {
        const float4* w = (const float4*)(out_w) + (size_t)t * 32;
        float a = out_b[t];
#pragma unroll 8
        for (int dq = 0; dq < 32; ++dq) a += dot4(z4[dq], w[dq]);
        v1s[t] = a;
    } else {
        int f = t - 128;
        const float4* w = (const float4*)(qia_in_w) + (size_t)(256 + f) * 32;
        float a = qia_in_b[256 + f];
#pragma unroll 8
        for (int dq = 0; dq < 32; ++dq) a += dot4(mm4[dq], w[dq]);
        ((float*)tq4)[f] = a;
    }
    __syncthreads();
    // phase B: v2[f] = tq . qia_out_w[f] + qia_out_b[f]
    if (t < 128) {
        const float4* w = (const float4*)(qia_out_w) + (size_t)t * 32;
        float a = qia_out_b[t];
#pragma unroll 8
        for (int dq = 0; dq < 32; ++dq) a += dot4(tq4[dq], w[dq]);
        v2s[t] = a;
    }
    __syncthreads();
    // phase C: base[b] = q.sw0 + v1.sw1 + v2.sw2 + score_b
    if (t < 128) {
        red[t] = query[(size_t)b * Dd + t] * score_w[t]
               + v1s[t] * score_w[128 + t]
               + v2s[t] * score_w[256 + t];
    }
    __syncthreads();
    for (int s = 64; s > 0; s >>= 1) {
        if (t < s) red[t] += red[t + s];
        __syncthreads();
    }
    if (t == 0) basev[b] = red[0] + score_b[0];
}

// ---------------- Kernel 4a: cand scores -> exp, per-b sum ---------------
// grid = B*P*8 = 2048 blocks, 256 threads; each block does 128 candidates
__global__ __launch_bounds__(256) void k_score(
    const float* __restrict__ cand_emb, const int* __restrict__ cand_len,
    const float* __restrict__ score_w, const float* __restrict__ basev,
    float* __restrict__ eout, float* __restrict__ sumexp)
{
    int blk = blockIdx.x;
    int chunk = blk & 7;
    int bp = blk >> 3;
    int b = bp >> 4;
    int t = threadIdx.x;
    int quad = t & 31, cl = t >> 5;   // 8 candidates concurrently
    float4 swq = ((const float4*)(score_w + 384))[quad];
    float bb = basev[b];
    int clen = cand_len[bp];
    const float4* cbase = (const float4*)(cand_emb + ((size_t)bp * Cc + chunk * 128) * Dd);
    float lsum = 0.f;
#pragma unroll 4
    for (int it = 0; it < 16; ++it) {
        int c = cl + it * 8;          // local candidate 0..127
        float4 v = cbase[(size_t)c * 32 + quad];
        float part = dot4(v, swq);
        part += __shfl_xor(part, 16);
        part += __shfl_xor(part, 8);
        part += __shfl_xor(part, 4);
        part += __shfl_xor(part, 2);
        part += __shfl_xor(part, 1);
        int gc = chunk * 128 + c;
        float e = (gc < clen) ? expf(part + bb) : 0.0f;
        if (quad == 0) {
            eout[(size_t)bp * Cc + gc] = e;
            lsum += e;
        }
    }
    __shared__ float red[256];
    red[t] = lsum;
    __syncthreads();
    for (int s = 128; s > 0; s >>= 1) {
        if (t < s) red[t] += red[t + s];
        __syncthreads();
    }
    if (t == 0) atomicAdd(&sumexp[b], red[0]);
}

// ---------------- Kernel 4b: normalize ------------------------------------
// grid = 256 blocks * 256 threads, one float4 each (65536 float4 total)
__global__ __launch_bounds__(256) void k_norm(
    float* __restrict__ out, const float* __restrict__ sumexp)
{
    int idx = blockIdx.x * 256 + threadIdx.x;
    int b = idx >> 12;  // 4096 float4 per batch
    float inv = 1.0f / sumexp[b];
    float4* o4 = (float4*)out;
    float4 v = o4[idx];
    v.x *= inv; v.y *= inv; v.z *= inv; v.w *= inv;
    o4[idx] = v;
}

extern "C" void kernel_launch(void* const* d_in, const int* in_sizes, int n_in,
                              void* d_out, int out_size, void* d_ws, size_t ws_size,
                              hipStream_t stream)
{
    const float* query    = (const float*)d_in[0];
    const float* path_emb = (const float*)d_in[1];
    const int*   path_len = (const int*)  d_in[2];
    const float* cand_emb = (const float*)d_in[3];
    const int*   cand_len = (const int*)  d_in[4];
    const float* conv_w   = (const float*)d_in[5];
    const float* conv_b   = (const float*)d_in[6];
    const float* pia_in_w = (const float*)d_in[7];
    const float* pia_in_b = (const float*)d_in[8];
    const float* pia_out_w= (const float*)d_in[9];
    const float* pia_out_b= (const float*)d_in[10];
    const float* mpa_in_w = (const float*)d_in[11];
    const float* mpa_in_b = (const float*)d_in[12];
    const float* mpa_out_w= (const float*)d_in[13];
    const float* mpa_out_b= (const float*)d_in[14];
    const float* qia_in_w = (const float*)d_in[15];
    const float* qia_in_b = (const float*)d_in[16];
    const float* qia_out_w= (const float*)d_in[17];
    const float* qia_out_b= (const float*)d_in[18];
    const float* score_w  = (const float*)d_in[19];
    const float* score_b  = (const float*)d_in[20];
    float* out = (float*)d_out;

    float* ws     = (float*)d_ws;
    float* inst   = ws;                       // B*P*I*F = 524288 floats
    float* meta   = ws + 524288;              // B*P*F   = 32768
    float* basev  = ws + 524288 + 32768;      // B       = 16
    float* sumexp = basev + 16;               // B       = 16
    float* qkv    = ws;                       // 16*16*384 = 98304, reuses dead inst

    hipMemsetAsync(sumexp, 0, Bb * sizeof(float), stream);

    k_mean_conv<<<Bb * Pp * Ii, 256, 0, stream>>>(path_emb, path_len, conv_w, conv_b, inst);
    k_pia<<<Bb * Pp, 256, 0, stream>>>(inst, pia_in_w, pia_in_b, pia_out_w, pia_out_b, meta);
    k_mpa_qkv<<<Bb * 24, 256, 0, stream>>>(meta, mpa_in_w, mpa_in_b, qkv);
    k_mpa_post<<<Bb, 256, 0, stream>>>(qkv, meta, query,
                                       mpa_out_w, mpa_out_b,
                                       qia_in_w, qia_in_b, qia_out_w, qia_out_b,
                                       score_w, score_b, basev);
    k_score<<<Bb * Pp * 8, 256, 0, stream>>>(cand_emb, cand_len, score_w, basev, out, sumexp);
    k_norm<<<256, 256, 0, stream>>>(out, sumexp);
}